// Round 1
// baseline (1669.176 us; speedup 1.0000x reference)
//
#include <hip/hip_runtime.h>
#include <math.h>

#define HID 128

// DPP-based wave64 reduction stage: v += dpp_shifted(v)
template<int CTRL, int RMASK>
__device__ __forceinline__ float dpp_add_stage(float v) {
  int s = __builtin_amdgcn_update_dpp(0, __float_as_int(v), CTRL, RMASK, 0xf, true);
  return v + __int_as_float(s);
}

// Full 64-lane sum, result broadcast to all lanes (via readlane 63 -> SGPR).
__device__ __forceinline__ float wave_red_sum(float v) {
  v = dpp_add_stage<0x111, 0xf>(v);  // row_shr:1
  v = dpp_add_stage<0x112, 0xf>(v);  // row_shr:2
  v = dpp_add_stage<0x114, 0xf>(v);  // row_shr:4
  v = dpp_add_stage<0x118, 0xf>(v);  // row_shr:8  -> lane15 of each row holds row sum
  v = dpp_add_stage<0x142, 0xa>(v);  // row_bcast:15 into rows 1,3
  v = dpp_add_stage<0x143, 0xc>(v);  // row_bcast:31 into rows 2,3 -> lane63 = total
  return __int_as_float(__builtin_amdgcn_readlane(__float_as_int(v), 63));
}

// One wave (64 lanes) per batch element. Lane l owns hidden rows l and l+64.
// W_in rows live in 256 VGPRs as float2 {row_l, row_l+64} pairs, k-major.
__global__ __launch_bounds__(64, 1) void snn_fused_kernel(
    const float* __restrict__ x, const float* __restrict__ Win,
    const float* __restrict__ b_in, const float* __restrict__ ln_g,
    const float* __restrict__ ln_b, const float* __restrict__ Wout,
    const float* __restrict__ b_out, float* __restrict__ out, int T) {
  __shared__ float4 xrow4[512];   // this block's x row: [T][4] (T<=512)
  __shared__ float4 enc4[32];     // 128 encoding values for current step

  const int b = blockIdx.x;
  const int lane = threadIdx.x;   // 0..63

  // Stage x[b, :, :] into LDS (coalesced float4 loads).
  const float4* xg = (const float4*)(x + (size_t)b * (size_t)T * 4);
  for (int i = lane; i < T; i += 64) xrow4[i] = xg[i];

  // Load W_in rows lane and lane+64 into registers (L2-resident after first blocks).
  float2 w[128];
  {
    const float4* rA = (const float4*)(Win + lane * HID);
    const float4* rB = (const float4*)(Win + (lane + 64) * HID);
#pragma unroll
    for (int q = 0; q < 32; ++q) {
      float4 a = rA[q], bb = rB[q];
      w[4*q+0] = make_float2(a.x, bb.x);
      w[4*q+1] = make_float2(a.y, bb.y);
      w[4*q+2] = make_float2(a.z, bb.z);
      w[4*q+3] = make_float2(a.w, bb.w);
    }
  }

  // Per-lane constants for rows lane (A) and lane+64 (B).
  const float binA = b_in[lane],      binB = b_in[lane + 64];
  const float gA   = ln_g[lane],      gB   = ln_g[lane + 64];
  const float bA   = ln_b[lane],      bB   = ln_b[lane + 64];
  const float woA0 = Wout[lane],      woB0 = Wout[lane + 64];
  const float woA1 = Wout[HID+lane],  woB1 = Wout[HID+lane + 64];

  // thresholds = linspace(-3,3,32): f64 math then cast, matching numpy.
  // k0 = lane -> channel (lane<32?0:1), thr index lane&31
  // k1 = lane+64 -> channel (lane<32?2:3), same thr index
  const float th   = (float)(-3.0 + (double)(lane & 31) * (6.0 / 31.0));
  const float coef = (float)(-0.5 * 1024.0 / 25.0);  // -0.5/sigma^2, sigma^2=25/1024

  float mem0 = 0.f, mem1 = 0.f;
  float ro0 = 0.f, ro1 = 0.f;   // per-lane readout partials (reduced once at end)

  __syncthreads();

  for (int t = 0; t < T; ++t) {
    float4 xt = xrow4[t];                       // uniform LDS read
    float xc0 = (lane < 32) ? xt.x : xt.y;
    float xc1 = (lane < 32) ? xt.z : xt.w;
    float d0 = xc0 - th, d1 = xc1 - th;
    float e0 = __expf(coef * d0 * d0);
    float e1 = __expf(coef * d1 * d1);
    ((float*)enc4)[lane]      = e0;
    ((float*)enc4)[lane + 64] = e1;
    __syncthreads();                            // enc visible to all lanes

    // h = W_in @ enc : 4 independent FMA chains per row for ILP.
    float2 a0 = make_float2(0.f, 0.f), a1 = a0, a2 = a0, a3 = a0;
#pragma unroll
    for (int q = 0; q < 32; ++q) {
      float4 e = enc4[q];                       // uniform b128 broadcast read
      float2 w0 = w[4*q+0], w1 = w[4*q+1], w2 = w[4*q+2], w3 = w[4*q+3];
      a0.x = fmaf(w0.x, e.x, a0.x); a0.y = fmaf(w0.y, e.x, a0.y);
      a1.x = fmaf(w1.x, e.y, a1.x); a1.y = fmaf(w1.y, e.y, a1.y);
      a2.x = fmaf(w2.x, e.z, a2.x); a2.y = fmaf(w2.y, e.z, a2.y);
      a3.x = fmaf(w3.x, e.w, a3.x); a3.y = fmaf(w3.y, e.w, a3.y);
    }
    float h0 = ((a0.x + a1.x) + (a2.x + a3.x)) + binA;
    float h1 = ((a0.y + a1.y) + (a2.y + a3.y)) + binB;

    // LayerNorm over 128 hidden units (2 per lane), DPP reductions.
    float s1 = wave_red_sum(h0 + h1);
    float s2 = wave_red_sum(fmaf(h0, h0, h1 * h1));
    float mu   = s1 * (1.0f / 128.0f);
    float var  = s2 * (1.0f / 128.0f) - mu * mu;
    float rstd = 1.0f / sqrtf(var + 1e-5f);
    float c0 = fmaf((h0 - mu) * rstd, gA, bA);
    float c1 = fmaf((h1 - mu) * rstd, gB, bB);

    // Leaky membrane + spike + soft reset + readout partials.
    mem0 = fmaf(mem0, 0.9f, c0 * 0.1f);
    mem1 = fmaf(mem1, 0.9f, c1 * 0.1f);
    float sp0 = (mem0 > 0.5f) ? 1.0f : 0.0f;    // == (mem-0.5 > 0) exactly in f32
    float sp1 = (mem1 > 0.5f) ? 1.0f : 0.0f;
    mem0 = fmaf(sp0, -0.5f, mem0);
    mem1 = fmaf(sp1, -0.5f, mem1);
    ro0 = fmaf(sp0, woA0, ro0); ro0 = fmaf(sp1, woB0, ro0);
    ro1 = fmaf(sp0, woA1, ro1); ro1 = fmaf(sp1, woB1, ro1);
    // No barrier needed before next enc write: single-wave lockstep + in-order DS pipe.
  }

  float R0 = wave_red_sum(ro0);
  float R1 = wave_red_sum(ro1);
  if (lane == 0) {
    out[2*b]     = R0 + (float)T * b_out[0];
    out[2*b + 1] = R1 + (float)T * b_out[1];
  }
}

extern "C" void kernel_launch(void* const* d_in, const int* in_sizes, int n_in,
                              void* d_out, int out_size, void* d_ws, size_t ws_size,
                              hipStream_t stream) {
  const float* x    = (const float*)d_in[0];
  const float* Win  = (const float*)d_in[1];
  const float* bin  = (const float*)d_in[2];
  const float* lng  = (const float*)d_in[3];
  const float* lnb  = (const float*)d_in[4];
  const float* Wout = (const float*)d_in[5];
  const float* bout = (const float*)d_in[6];
  float* out = (float*)d_out;

  int B = out_size / 2;                 // 2048
  int T = in_sizes[0] / (B * 4);        // 512

  snn_fused_kernel<<<dim3(B), dim3(64), 0, stream>>>(
      x, Win, bin, lng, lnb, Wout, bout, out, T);
}